// Round 1
// baseline (4278.761 us; speedup 1.0000x reference)
//
#include <hip/hip_runtime.h>
#include <math.h>

#define Bn 4
#define Ln 1024
#define Dn 128
#define Hn 8
#define Gn 64
#define NITERS 4
#define NEGV -1000000000.0f

// ---------------- repack ternary/global into contiguous per-head layouts ----
// Tp[h][a][b] = ternary[a,b,h]; Tpt[h][b][a] = ternary[a,b,h]; Gp[h][g][a] = global_[g,a,h]
__global__ void repack_kernel(const float* __restrict__ ter, const float* __restrict__ glb,
                              float* __restrict__ Tp, float* __restrict__ Tpt,
                              float* __restrict__ Gp) {
    int idx = blockIdx.x * 256 + threadIdx.x;
    if (idx < Dn * Dn * Hn) {
        int h = idx % Hn; int ab = idx / Hn; int b = ab % Dn; int a = ab / Dn;
        float v = ter[idx];
        Tp[((size_t)h * Dn + a) * Dn + b] = v;
        Tpt[((size_t)h * Dn + b) * Dn + a] = v;
    }
    if (idx < Gn * Dn * Hn) {
        int h = idx % Hn; int ga = idx / Hn; int a = ga % Dn; int g = ga / Dn;
        Gp[((size_t)h * Gn + g) * Dn + a] = glb[idx];
    }
}

// ---------------- row softmax over D=128, one block of 128 threads per row --
__global__ void softmax_rows_kernel(const float* __restrict__ in, float* __restrict__ out) {
    int row = blockIdx.x;
    int t = threadIdx.x;  // 0..127
    __shared__ float red[2];
    float v = in[(size_t)row * Dn + t];
    float m = v;
    #pragma unroll
    for (int off = 1; off < 64; off <<= 1) m = fmaxf(m, __shfl_xor(m, off, 64));
    if ((t & 63) == 0) red[t >> 6] = m;
    __syncthreads();
    m = fmaxf(red[0], red[1]);
    float e = expf(v - m);
    float s = e;
    #pragma unroll
    for (int off = 1; off < 64; off <<= 1) s += __shfl_xor(s, off, 64);
    __syncthreads();
    if ((t & 63) == 0) red[t >> 6] = s;
    __syncthreads();
    s = red[0] + red[1];
    out[(size_t)row * Dn + t] = e / s;
}

// ---------------- Out[n,h,j,c] = sum_k Qz[n,j,k] * M[h,c,k]  (U and V) ------
__launch_bounds__(256)
__global__ void uv_kernel(const float* __restrict__ Qz, const float* __restrict__ M,
                          float* __restrict__ Out) {
    int jt = blockIdx.x;  // 0..31 (32-row j tiles)
    int h  = blockIdx.y;
    int n  = blockIdx.z;
    int t  = threadIdx.x;
    __shared__ float Qs[32][Dn];
    __shared__ float Ms[Dn][17];   // k-chunk of 16, padded
    const float* Qbase = Qz + ((size_t)n * Ln + jt * 32) * Dn;
    const float* Mh = M + (size_t)h * Dn * Dn;
    float* Obase = Out + (((size_t)n * Hn + h) * Ln + (size_t)jt * 32) * Dn;
    for (int i = t; i < 32 * (Dn / 4); i += 256) {
        int r = i >> 5, c4 = i & 31;
        ((float4*)&Qs[r][0])[c4] = ((const float4*)(Qbase + (size_t)r * Dn))[c4];
    }
    int jm = (t >> 5) * 4;  // 4 j rows
    int cl = t & 31;        // c = cl + 32*cc
    float acc[4][4];
    #pragma unroll
    for (int a = 0; a < 4; a++)
        #pragma unroll
        for (int b = 0; b < 4; b++) acc[a][b] = 0.f;
    for (int k0 = 0; k0 < Dn; k0 += 16) {
        __syncthreads();
        for (int i = t; i < Dn * 16; i += 256) {
            int c = i >> 4, kk = i & 15;
            Ms[c][kk] = Mh[(size_t)c * Dn + k0 + kk];
        }
        __syncthreads();
        #pragma unroll
        for (int kk = 0; kk < 16; kk++) {
            float q0 = Qs[jm + 0][k0 + kk], q1 = Qs[jm + 1][k0 + kk];
            float q2 = Qs[jm + 2][k0 + kk], q3 = Qs[jm + 3][k0 + kk];
            float m0 = Ms[cl][kk], m1 = Ms[cl + 32][kk];
            float m2 = Ms[cl + 64][kk], m3 = Ms[cl + 96][kk];
            acc[0][0] += q0 * m0; acc[0][1] += q0 * m1; acc[0][2] += q0 * m2; acc[0][3] += q0 * m3;
            acc[1][0] += q1 * m0; acc[1][1] += q1 * m1; acc[1][2] += q1 * m2; acc[1][3] += q1 * m3;
            acc[2][0] += q2 * m0; acc[2][1] += q2 * m1; acc[2][2] += q2 * m2; acc[2][3] += q2 * m3;
            acc[3][0] += q3 * m0; acc[3][1] += q3 * m1; acc[3][2] += q3 * m2; acc[3][3] += q3 * m3;
        }
    }
    #pragma unroll
    for (int jj = 0; jj < 4; jj++)
        #pragma unroll
        for (int cc = 0; cc < 4; cc++)
            Obase[(size_t)(jm + jj) * Dn + cl + 32 * cc] = acc[jj][cc];
}

// ---------------- msg_i + msg_g: flash-style online softmax over j tiles ----
// grid (L/64, H, B). Tile jt==16 is the G=64 global-node tile (unmasked).
__launch_bounds__(256, 1)
__global__ void msgi_kernel(const float* __restrict__ Qz, const float* __restrict__ U,
                            const float* __restrict__ Gp, const int* __restrict__ mask,
                            float* __restrict__ Fz, float* __restrict__ rowM,
                            float* __restrict__ rowL) {
    int it = blockIdx.x;  // i tile, 0..15
    int h  = blockIdx.y;
    int n  = blockIdx.z;
    int t  = threadIdx.x;

    __shared__ float Qs[64][132];
    __shared__ float Us[64][132];
    __shared__ float Ps[64][65];
    __shared__ float mrow[64], lrow[64], arow[64];
    __shared__ int imaskS[64], jmaskS[64];

    const float* Qbase = Qz + ((size_t)n * Ln + it * 64) * Dn;
    for (int i = t; i < 64 * 32; i += 256) {
        int r = i >> 5, c4 = i & 31;
        *((float4*)&Qs[r][c4 * 4]) = ((const float4*)(Qbase + (size_t)r * Dn))[c4];
    }
    if (t < 64) {
        imaskS[t] = mask[n * Ln + it * 64 + t];
        mrow[t] = -3.0e38f;
        lrow[t] = 0.0f;
    }

    int iy = (t >> 3) * 2;  // acc row pair
    int cl = t & 7;         // acc col group: c = cl*4 + 32*f
    float4 acc0[4], acc1[4];
    #pragma unroll
    for (int f = 0; f < 4; f++) { acc0[f] = make_float4(0,0,0,0); acc1[f] = make_float4(0,0,0,0); }

    int sr = t >> 4;  // score rows sr + 16*ii
    int sc = t & 15;  // score cols sc + 16*jj

    const float* Ubase = U + ((size_t)n * Hn + h) * Ln * Dn;
    const float* Gbase = Gp + (size_t)h * Gn * Dn;

    for (int jt = 0; jt < 17; jt++) {
        __syncthreads();
        const float* src = (jt < 16) ? (Ubase + (size_t)jt * 64 * Dn) : Gbase;
        for (int i = t; i < 64 * 32; i += 256) {
            int r = i >> 5, c4 = i & 31;
            *((float4*)&Us[r][c4 * 4]) = ((const float4*)(src + (size_t)r * Dn))[c4];
        }
        if (t < 64) jmaskS[t] = (jt < 16) ? mask[n * Ln + jt * 64 + t] : 1;
        __syncthreads();

        // 4x4 score micro-tile
        float s[4][4];
        #pragma unroll
        for (int ii = 0; ii < 4; ii++)
            #pragma unroll
            for (int jj = 0; jj < 4; jj++) s[ii][jj] = 0.f;
        for (int k0 = 0; k0 < Dn; k0 += 4) {
            float4 q[4], u[4];
            #pragma unroll
            for (int ii = 0; ii < 4; ii++) q[ii] = *((const float4*)&Qs[sr + 16 * ii][k0]);
            #pragma unroll
            for (int jj = 0; jj < 4; jj++) u[jj] = *((const float4*)&Us[sc + 16 * jj][k0]);
            #pragma unroll
            for (int ii = 0; ii < 4; ii++)
                #pragma unroll
                for (int jj = 0; jj < 4; jj++)
                    s[ii][jj] += q[ii].x * u[jj].x + q[ii].y * u[jj].y +
                                 q[ii].z * u[jj].z + q[ii].w * u[jj].w;
        }
        bool isg = (jt == 16);
        #pragma unroll
        for (int ii = 0; ii < 4; ii++) {
            int ri = sr + 16 * ii;
            bool vi = imaskS[ri] != 0;
            #pragma unroll
            for (int jj = 0; jj < 4; jj++) {
                int cj = sc + 16 * jj;
                float sv = s[ii][jj];
                if (!isg && (!vi || jmaskS[cj] == 0)) sv = NEGV;
                Ps[ri][cj] = sv;
            }
        }
        __syncthreads();

        // online softmax row update (wave 0, one row per lane)
        if (t < 64) {
            float mold = mrow[t];
            float mt = mold;
            for (int j = 0; j < 64; j++) mt = fmaxf(mt, Ps[t][j]);
            float alpha = expf(mold - mt);
            float sum = 0.f;
            for (int j = 0; j < 64; j++) {
                float p = expf(Ps[t][j] - mt);
                Ps[t][j] = p;
                sum += p;
            }
            mrow[t] = mt;
            lrow[t] = lrow[t] * alpha + sum;
            arow[t] = alpha;
        }
        __syncthreads();

        float a0 = arow[iy], a1 = arow[iy + 1];
        #pragma unroll
        for (int f = 0; f < 4; f++) {
            acc0[f].x *= a0; acc0[f].y *= a0; acc0[f].z *= a0; acc0[f].w *= a0;
            acc1[f].x *= a1; acc1[f].y *= a1; acc1[f].z *= a1; acc1[f].w *= a1;
        }
        for (int j = 0; j < 64; j++) {
            float p0 = Ps[iy][j], p1 = Ps[iy + 1][j];
            #pragma unroll
            for (int f = 0; f < 4; f++) {
                float4 u = *((const float4*)&Us[j][cl * 4 + 32 * f]);
                acc0[f].x += p0 * u.x; acc0[f].y += p0 * u.y; acc0[f].z += p0 * u.z; acc0[f].w += p0 * u.w;
                acc1[f].x += p1 * u.x; acc1[f].y += p1 * u.y; acc1[f].z += p1 * u.z; acc1[f].w += p1 * u.w;
            }
        }
    }
    __syncthreads();
    size_t rbase = ((size_t)n * Hn + h) * Ln + (size_t)it * 64;
    if (t < 64) {
        rowM[rbase + t] = mrow[t];
        rowL[rbase + t] = lrow[t];
    }
    float inv0 = 1.0f / lrow[iy];
    float inv1 = 1.0f / lrow[iy + 1];
    float* F0 = Fz + ((size_t)n * Ln + it * 64 + iy) * Dn;
    float* F1 = F0 + Dn;
    #pragma unroll
    for (int f = 0; f < 4; f++) {
        int c = cl * 4 + 32 * f;
        atomicAdd(&F0[c + 0], acc0[f].x * inv0);
        atomicAdd(&F0[c + 1], acc0[f].y * inv0);
        atomicAdd(&F0[c + 2], acc0[f].z * inv0);
        atomicAdd(&F0[c + 3], acc0[f].w * inv0);
        atomicAdd(&F1[c + 0], acc1[f].x * inv1);
        atomicAdd(&F1[c + 1], acc1[f].y * inv1);
        atomicAdd(&F1[c + 2], acc1[f].z * inv1);
        atomicAdd(&F1[c + 3], acc1[f].w * inv1);
    }
}

// ---------------- msg_j: P^T * V using stored row stats ---------------------
// grid (L/64, H, B); block owns a j tile, iterates i tiles.
__launch_bounds__(256, 1)
__global__ void msgj_kernel(const float* __restrict__ Qz, const float* __restrict__ U,
                            const float* __restrict__ V, const int* __restrict__ mask,
                            const float* __restrict__ rowM, const float* __restrict__ rowL,
                            float* __restrict__ Fz) {
    int jt = blockIdx.x;
    int h  = blockIdx.y;
    int n  = blockIdx.z;
    int t  = threadIdx.x;

    __shared__ float UsJ[64][132];
    __shared__ float Qs[64][132];
    __shared__ float Vs[64][132];
    __shared__ float Ps[64][65];   // [i_local][j_local]
    __shared__ float mI[64], linv[64];
    __shared__ int imaskS[64], jmaskS[64];

    const float* Ubase = U + ((size_t)n * Hn + h) * Ln * Dn + (size_t)jt * 64 * Dn;
    for (int i = t; i < 64 * 32; i += 256) {
        int r = i >> 5, c4 = i & 31;
        *((float4*)&UsJ[r][c4 * 4]) = ((const float4*)(Ubase + (size_t)r * Dn))[c4];
    }
    if (t < 64) jmaskS[t] = mask[n * Ln + jt * 64 + t];

    int jy = (t >> 3) * 2;  // acc row pair (j rows)
    int cl = t & 7;
    float4 acc0[4], acc1[4];
    #pragma unroll
    for (int f = 0; f < 4; f++) { acc0[f] = make_float4(0,0,0,0); acc1[f] = make_float4(0,0,0,0); }

    int sr = t >> 4;  // i rows sr + 16*ii
    int sc = t & 15;  // j cols sc + 16*jj
    size_t rbase = ((size_t)n * Hn + h) * Ln;

    for (int it2 = 0; it2 < 16; it2++) {
        __syncthreads();
        const float* Qb = Qz + ((size_t)n * Ln + it2 * 64) * Dn;
        const float* Vb = V + (rbase + (size_t)it2 * 64) * Dn;
        for (int i = t; i < 64 * 32; i += 256) {
            int r = i >> 5, c4 = i & 31;
            *((float4*)&Qs[r][c4 * 4]) = ((const float4*)(Qb + (size_t)r * Dn))[c4];
            *((float4*)&Vs[r][c4 * 4]) = ((const float4*)(Vb + (size_t)r * Dn))[c4];
        }
        if (t < 64) {
            imaskS[t] = mask[n * Ln + it2 * 64 + t];
            mI[t] = rowM[rbase + it2 * 64 + t];
            linv[t] = 1.0f / rowL[rbase + it2 * 64 + t];
        }
        __syncthreads();

        float s[4][4];
        #pragma unroll
        for (int ii = 0; ii < 4; ii++)
            #pragma unroll
            for (int jj = 0; jj < 4; jj++) s[ii][jj] = 0.f;
        for (int k0 = 0; k0 < Dn; k0 += 4) {
            float4 q[4], u[4];
            #pragma unroll
            for (int ii = 0; ii < 4; ii++) q[ii] = *((const float4*)&Qs[sr + 16 * ii][k0]);
            #pragma unroll
            for (int jj = 0; jj < 4; jj++) u[jj] = *((const float4*)&UsJ[sc + 16 * jj][k0]);
            #pragma unroll
            for (int ii = 0; ii < 4; ii++)
                #pragma unroll
                for (int jj = 0; jj < 4; jj++)
                    s[ii][jj] += q[ii].x * u[jj].x + q[ii].y * u[jj].y +
                                 q[ii].z * u[jj].z + q[ii].w * u[jj].w;
        }
        #pragma unroll
        for (int ii = 0; ii < 4; ii++) {
            int ri = sr + 16 * ii;
            bool vi = imaskS[ri] != 0;
            #pragma unroll
            for (int jj = 0; jj < 4; jj++) {
                int cj = sc + 16 * jj;
                float p = 0.f;
                if (vi && jmaskS[cj] != 0) p = expf(s[ii][jj] - mI[ri]) * linv[ri];
                Ps[ri][cj] = p;
            }
        }
        __syncthreads();

        for (int i = 0; i < 64; i++) {
            float p0 = Ps[i][jy], p1 = Ps[i][jy + 1];
            #pragma unroll
            for (int f = 0; f < 4; f++) {
                float4 v4 = *((const float4*)&Vs[i][cl * 4 + 32 * f]);
                acc0[f].x += p0 * v4.x; acc0[f].y += p0 * v4.y; acc0[f].z += p0 * v4.z; acc0[f].w += p0 * v4.w;
                acc1[f].x += p1 * v4.x; acc1[f].y += p1 * v4.y; acc1[f].z += p1 * v4.z; acc1[f].w += p1 * v4.w;
            }
        }
    }
    float* F0 = Fz + ((size_t)n * Ln + jt * 64 + jy) * Dn;
    float* F1 = F0 + Dn;
    #pragma unroll
    for (int f = 0; f < 4; f++) {
        int c = cl * 4 + 32 * f;
        atomicAdd(&F0[c + 0], acc0[f].x);
        atomicAdd(&F0[c + 1], acc0[f].y);
        atomicAdd(&F0[c + 2], acc0[f].z);
        atomicAdd(&F0[c + 3], acc0[f].w);
        atomicAdd(&F1[c + 0], acc1[f].x);
        atomicAdd(&F1[c + 1], acc1[f].y);
        atomicAdd(&F1[c + 2], acc1[f].z);
        atomicAdd(&F1[c + 3], acc1[f].w);
    }
}

__global__ void mask_out_kernel(float* __restrict__ Fz, const int* __restrict__ mask) {
    int idx = blockIdx.x * 256 + threadIdx.x;
    if (idx < Bn * Ln * Dn) {
        int row = idx / Dn;
        if (mask[row] == 0) Fz[idx] = 0.f;
    }
}

extern "C" void kernel_launch(void* const* d_in, const int* in_sizes, int n_in,
                              void* d_out, int out_size, void* d_ws, size_t ws_size,
                              hipStream_t stream) {
    const float* x       = (const float*)d_in[0];
    const int*   mask    = (const int*)d_in[1];
    const float* ternary = (const float*)d_in[2];
    const float* global_ = (const float*)d_in[3];
    float* out = (float*)d_out;

    float* ws = (float*)d_ws;
    size_t o = 0;
    float* Qz   = ws + o; o += (size_t)Bn * Ln * Dn;        // 524288
    float* U    = ws + o; o += (size_t)Bn * Hn * Ln * Dn;   // 4194304
    float* V    = ws + o; o += (size_t)Bn * Hn * Ln * Dn;   // 4194304
    float* Tp   = ws + o; o += (size_t)Hn * Dn * Dn;        // 131072
    float* Tpt  = ws + o; o += (size_t)Hn * Dn * Dn;        // 131072
    float* Gp   = ws + o; o += (size_t)Hn * Gn * Dn;        // 65536
    float* rowM = ws + o; o += (size_t)Bn * Hn * Ln;        // 32768
    float* rowL = ws + o; o += (size_t)Bn * Hn * Ln;        // 32768
    (void)ws_size; (void)n_in; (void)in_sizes; (void)out_size;

    repack_kernel<<<(Dn * Dn * Hn + 255) / 256, 256, 0, stream>>>(ternary, global_, Tp, Tpt, Gp);
    softmax_rows_kernel<<<Bn * Ln, 128, 0, stream>>>(x, Qz);

    for (int it = 0; it < NITERS; it++) {
        hipMemcpyAsync(out, x, sizeof(float) * Bn * Ln * Dn, hipMemcpyDeviceToDevice, stream);
        uv_kernel<<<dim3(Ln / 32, Hn, Bn), 256, 0, stream>>>(Qz, Tp, U);
        uv_kernel<<<dim3(Ln / 32, Hn, Bn), 256, 0, stream>>>(Qz, Tpt, V);
        msgi_kernel<<<dim3(Ln / 64, Hn, Bn), 256, 0, stream>>>(Qz, U, Gp, mask, out, rowM, rowL);
        msgj_kernel<<<dim3(Ln / 64, Hn, Bn), 256, 0, stream>>>(Qz, U, V, mask, rowM, rowL, out);
        if (it < NITERS - 1)
            softmax_rows_kernel<<<Bn * Ln, 128, 0, stream>>>(out, Qz);
    }
    mask_out_kernel<<<(Bn * Ln * Dn + 255) / 256, 256, 0, stream>>>(out, mask);
}

// Round 2
// 519.665 us; speedup vs baseline: 8.2337x; 8.2337x over previous
//
#include <hip/hip_runtime.h>
#include <math.h>

#define Bn 4
#define Ln 1024
#define Dn 128
#define Hn 8
#define Gn 64
#define NITERS 4
#define NEGV -1000000000.0f

typedef _Float16 f16;
typedef _Float16 half8 __attribute__((ext_vector_type(8)));
typedef _Float16 half4 __attribute__((ext_vector_type(4)));
typedef float floatx4 __attribute__((ext_vector_type(4)));

#define WPAD 136   // f16 row stride for 64x128 / 128x128 row-major tiles
#define UBPAD 72   // f16 row stride for 128x64 transposed tiles
#define PBPAD 72   // f16 row stride for wave-private P strips

#define MFMA(a, b, c) __builtin_amdgcn_mfma_f32_16x16x32_f16((a), (b), (c), 0, 0, 0)

// ---------------- repack ternary/global into f16 per-head layouts -----------
// TpA[h][a][b], TpB[h][b][a] from ternary[a,b,h]; GpA[h][g][a], Gpt[h][a][g]
__global__ void repack_kernel(const float* __restrict__ ter, const float* __restrict__ glb,
                              f16* __restrict__ TpA, f16* __restrict__ TpB,
                              f16* __restrict__ GpA, f16* __restrict__ Gpt) {
    int idx = blockIdx.x * 256 + threadIdx.x;
    if (idx < Dn * Dn * Hn) {
        int h = idx % Hn; int b = (idx / Hn) % Dn; int a = idx / (Hn * Dn);
        f16 v = (f16)ter[idx];
        TpA[((size_t)h * Dn + a) * Dn + b] = v;
        TpB[((size_t)h * Dn + b) * Dn + a] = v;
    }
    if (idx < Gn * Dn * Hn) {
        int h = idx % Hn; int a = (idx / Hn) % Dn; int g = idx / (Hn * Dn);
        f16 v = (f16)glb[idx];
        GpA[((size_t)h * Gn + g) * Dn + a] = v;
        Gpt[((size_t)h * Dn + a) * Gn + g] = v;
    }
}

// ---------------- row softmax over D=128 (fp32 in, f16 out) -----------------
__global__ void softmax_rows_kernel(const float* __restrict__ in, f16* __restrict__ out) {
    int row = blockIdx.x;
    int t = threadIdx.x;  // 0..127
    __shared__ float red[2];
    float v = in[(size_t)row * Dn + t];
    float m = v;
    #pragma unroll
    for (int off = 1; off < 64; off <<= 1) m = fmaxf(m, __shfl_xor(m, off, 64));
    if ((t & 63) == 0) red[t >> 6] = m;
    __syncthreads();
    m = fmaxf(red[0], red[1]);
    float e = __expf(v - m);
    float s = e;
    #pragma unroll
    for (int off = 1; off < 64; off <<= 1) s += __shfl_xor(s, off, 64);
    __syncthreads();
    if ((t & 63) == 0) red[t >> 6] = s;
    __syncthreads();
    s = red[0] + red[1];
    out[(size_t)row * Dn + t] = (f16)(e / s);
}

// ---------------- U/V projection via MFMA -----------------------------------
// U[n,h,j,a] = sum_b Qz[n,j,b] * TpA[h,a,b];  also Ut[n,h,a,j]
// V[n,h,i,b] = sum_a Qz[n,i,a] * TpB[h,b,a];  stored only as Vt[n,h,b,i]
__launch_bounds__(256, 4)
__global__ void uv_kernel(const f16* __restrict__ Qz, const f16* __restrict__ TpA,
                          const f16* __restrict__ TpB,
                          f16* __restrict__ U, f16* __restrict__ Ut, f16* __restrict__ Vt) {
    int bx = blockIdx.x;  // 16 j-strips of 64
    int h  = blockIdx.y;
    int n  = blockIdx.z;
    int t  = threadIdx.x;
    int w = t >> 6, l = t & 63, m = l & 15, q = l >> 4;

    __shared__ __align__(16) f16 Ts[128 * WPAD];

    // preload A-fragments (Qz rows) straight from global
    int jrow = bx * 64 + w * 16 + m;
    const f16* qbase = Qz + ((size_t)n * Ln + jrow) * Dn;
    half8 aq[4];
    #pragma unroll
    for (int ks = 0; ks < 4; ks++)
        aq[ks] = *(const half8*)(qbase + ks * 32 + q * 8);

    size_t hoff = (size_t)(n * Hn + h);
    int jr0 = bx * 64 + w * 16 + 4 * q;

    // ---- pass 1: U = Qz * TpA^T ----
    {
        const f16* src = TpA + (size_t)h * Dn * Dn;
        for (int ii = 0; ii < 8; ii++) {
            int idx = t + 256 * ii; int r = idx >> 4, c = idx & 15;
            *(float4*)&Ts[r * WPAD + c * 8] = *(const float4*)(src + (size_t)r * Dn + c * 8);
        }
        __syncthreads();
        #pragma unroll
        for (int ct = 0; ct < 8; ct++) {
            floatx4 acc = {0.f, 0.f, 0.f, 0.f};
            #pragma unroll
            for (int ks = 0; ks < 4; ks++) {
                half8 b = *(const half8*)&Ts[(ct * 16 + m) * WPAD + ks * 32 + q * 8];
                acc = MFMA(aq[ks], b, acc);
            }
            f16* ub = U + (hoff * Ln + jr0) * Dn + ct * 16 + m;
            #pragma unroll
            for (int reg = 0; reg < 4; reg++) ub[(size_t)reg * Dn] = (f16)acc[reg];
            half4 pk = { (f16)acc[0], (f16)acc[1], (f16)acc[2], (f16)acc[3] };
            *(half4*)(Ut + (hoff * Dn + ct * 16 + m) * Ln + jr0) = pk;
        }
        __syncthreads();
    }
    // ---- pass 2: V = Qz * TpB^T, stored transposed ----
    {
        const f16* src = TpB + (size_t)h * Dn * Dn;
        for (int ii = 0; ii < 8; ii++) {
            int idx = t + 256 * ii; int r = idx >> 4, c = idx & 15;
            *(float4*)&Ts[r * WPAD + c * 8] = *(const float4*)(src + (size_t)r * Dn + c * 8);
        }
        __syncthreads();
        #pragma unroll
        for (int ct = 0; ct < 8; ct++) {
            floatx4 acc = {0.f, 0.f, 0.f, 0.f};
            #pragma unroll
            for (int ks = 0; ks < 4; ks++) {
                half8 b = *(const half8*)&Ts[(ct * 16 + m) * WPAD + ks * 32 + q * 8];
                acc = MFMA(aq[ks], b, acc);
            }
            half4 pk = { (f16)acc[0], (f16)acc[1], (f16)acc[2], (f16)acc[3] };
            *(half4*)(Vt + (hoff * Dn + ct * 16 + m) * Ln + jr0) = pk;
        }
    }
}

// ---------------- msg_i + msg_g: MFMA flash with wave-local online softmax --
__launch_bounds__(256, 3)
__global__ void msgi_kernel(const f16* __restrict__ Qz, const f16* __restrict__ U,
                            const f16* __restrict__ Ut, const f16* __restrict__ GpA,
                            const f16* __restrict__ Gpt, const int* __restrict__ mask,
                            f16* __restrict__ Macc, float* __restrict__ rowM,
                            float* __restrict__ rowL) {
    int it = blockIdx.x, h = blockIdx.y, n = blockIdx.z;
    int t = threadIdx.x;
    int w = t >> 6, l = t & 63, m = l & 15, q = l >> 4;

    __shared__ __align__(16) f16 Us[64 * WPAD];   // Qz tile first, then U tiles
    __shared__ __align__(16) f16 Ub[128 * UBPAD];
    __shared__ __align__(16) f16 Pb[4 * 16 * PBPAD];
    __shared__ int jms[64];

    // stage Qz tile, preload A-fragments
    {
        const f16* src = Qz + ((size_t)n * Ln + it * 64) * Dn;
        for (int ii = 0; ii < 4; ii++) {
            int idx = t + 256 * ii; int r = idx >> 4, c = idx & 15;
            *(float4*)&Us[r * WPAD + c * 8] = *(const float4*)(src + (size_t)r * Dn + c * 8);
        }
    }
    __syncthreads();
    half8 aq[4];
    #pragma unroll
    for (int ks = 0; ks < 4; ks++)
        aq[ks] = *(const half8*)&Us[(w * 16 + m) * WPAD + ks * 32 + q * 8];
    int im[4];
    #pragma unroll
    for (int reg = 0; reg < 4; reg++)
        im[reg] = mask[n * Ln + it * 64 + w * 16 + 4 * q + reg];
    __syncthreads();

    float m_run[4], l_run[4];
    #pragma unroll
    for (int reg = 0; reg < 4; reg++) { m_run[reg] = -3.0e38f; l_run[reg] = 0.f; }
    floatx4 Oacc[8];
    #pragma unroll
    for (int c = 0; c < 8; c++) Oacc[c] = (floatx4){0.f, 0.f, 0.f, 0.f};

    size_t hoff = (size_t)(n * Hn + h);
    f16* Pw = &Pb[w * 16 * PBPAD];

    for (int jt = 0; jt < 17; jt++) {
        const f16* usrc; const f16* ubsrc; size_t ubstride;
        if (jt < 16) {
            usrc = U + (hoff * Ln + jt * 64) * Dn;
            ubsrc = Ut + hoff * Dn * Ln + jt * 64;
            ubstride = Ln;
        } else {
            usrc = GpA + (size_t)h * Gn * Dn;
            ubsrc = Gpt + (size_t)h * Dn * Gn;
            ubstride = Gn;
        }
        for (int ii = 0; ii < 4; ii++) {
            int idx = t + 256 * ii; int r = idx >> 4, c = idx & 15;
            *(float4*)&Us[r * WPAD + c * 8] = *(const float4*)(usrc + (size_t)r * Dn + c * 8);
        }
        for (int ii = 0; ii < 4; ii++) {
            int idx = t + 256 * ii; int r = idx >> 3, c = idx & 7;
            *(float4*)&Ub[r * UBPAD + c * 8] = *(const float4*)(ubsrc + (size_t)r * ubstride + c * 8);
        }
        if (t < 64) jms[t] = (jt < 16) ? mask[n * Ln + jt * 64 + t] : 1;
        __syncthreads();

        // scores: S[i=4q+reg (wave strip)][j=16ct+m]
        floatx4 s[4];
        #pragma unroll
        for (int ct = 0; ct < 4; ct++) {
            floatx4 acc = {0.f, 0.f, 0.f, 0.f};
            #pragma unroll
            for (int ks = 0; ks < 4; ks++) {
                half8 b = *(const half8*)&Us[(ct * 16 + m) * WPAD + ks * 32 + q * 8];
                acc = MFMA(aq[ks], b, acc);
            }
            s[ct] = acc;
        }
        if (jt < 16) {
            #pragma unroll
            for (int ct = 0; ct < 4; ct++) {
                int jv = jms[ct * 16 + m];
                #pragma unroll
                for (int reg = 0; reg < 4; reg++)
                    if (!(im[reg] && jv)) s[ct][reg] = NEGV;
            }
        }
        // wave-local online softmax (rows live in quads)
        float alpha[4];
        #pragma unroll
        for (int reg = 0; reg < 4; reg++) {
            float mt = fmaxf(fmaxf(s[0][reg], s[1][reg]), fmaxf(s[2][reg], s[3][reg]));
            #pragma unroll
            for (int off = 1; off < 16; off <<= 1) mt = fmaxf(mt, __shfl_xor(mt, off, 64));
            float mnew = fmaxf(m_run[reg], mt);
            alpha[reg] = __expf(m_run[reg] - mnew);
            float rs = 0.f;
            #pragma unroll
            for (int ct = 0; ct < 4; ct++) {
                float p = __expf(s[ct][reg] - mnew);
                s[ct][reg] = p;
                rs += p;
            }
            #pragma unroll
            for (int off = 1; off < 16; off <<= 1) rs += __shfl_xor(rs, off, 64);
            l_run[reg] = l_run[reg] * alpha[reg] + rs;
            m_run[reg] = mnew;
        }
        #pragma unroll
        for (int c = 0; c < 8; c++)
            #pragma unroll
            for (int reg = 0; reg < 4; reg++) Oacc[c][reg] *= alpha[reg];
        // P -> wave-private LDS strip (f16)
        #pragma unroll
        for (int ct = 0; ct < 4; ct++)
            #pragma unroll
            for (int reg = 0; reg < 4; reg++)
                Pw[(4 * q + reg) * PBPAD + ct * 16 + m] = (f16)s[ct][reg];
        // O += P * U
        #pragma unroll
        for (int ks2 = 0; ks2 < 2; ks2++) {
            half8 ap = *(const half8*)&Pw[m * PBPAD + ks2 * 32 + q * 8];
            #pragma unroll
            for (int c = 0; c < 8; c++) {
                half8 bu = *(const half8*)&Ub[(c * 16 + m) * UBPAD + ks2 * 32 + q * 8];
                Oacc[c] = MFMA(ap, bu, Oacc[c]);
            }
        }
        __syncthreads();
    }

    // epilogue
    size_t rb = hoff * Ln + it * 64 + w * 16 + 4 * q;
    if (m == 0) {
        #pragma unroll
        for (int reg = 0; reg < 4; reg++) { rowM[rb + reg] = m_run[reg]; rowL[rb + reg] = l_run[reg]; }
    }
    f16* Mo = Macc + rb * Dn;
    #pragma unroll
    for (int reg = 0; reg < 4; reg++) {
        float inv = 1.0f / l_run[reg];
        #pragma unroll
        for (int c = 0; c < 8; c++)
            Mo[(size_t)reg * Dn + c * 16 + m] = (f16)(Oacc[c][reg] * inv);
    }
}

// ---------------- msg_j: P^T * V with stored row stats ----------------------
__launch_bounds__(256, 3)
__global__ void msgj_kernel(const f16* __restrict__ Qz, const f16* __restrict__ U,
                            const f16* __restrict__ Vt, const int* __restrict__ mask,
                            const float* __restrict__ rowM, const float* __restrict__ rowL,
                            f16* __restrict__ Macc) {
    int jt = blockIdx.x, h = blockIdx.y, n = blockIdx.z;
    int t = threadIdx.x;
    int w = t >> 6, l = t & 63, m = l & 15, q = l >> 4;

    __shared__ __align__(16) f16 Qb[64 * WPAD];   // U j-tile first, then Qz i-tiles
    __shared__ __align__(16) f16 Vb[128 * UBPAD];
    __shared__ __align__(16) f16 Pb[4 * 16 * PBPAD];
    __shared__ float mIs[64], lIs[64];
    __shared__ int ims[64];

    size_t hoff = (size_t)(n * Hn + h);

    // stage U j-tile rows, preload A-fragments
    {
        const f16* src = U + (hoff * Ln + jt * 64) * Dn;
        for (int ii = 0; ii < 4; ii++) {
            int idx = t + 256 * ii; int r = idx >> 4, c = idx & 15;
            *(float4*)&Qb[r * WPAD + c * 8] = *(const float4*)(src + (size_t)r * Dn + c * 8);
        }
    }
    __syncthreads();
    half8 au[4];
    #pragma unroll
    for (int ks = 0; ks < 4; ks++)
        au[ks] = *(const half8*)&Qb[(w * 16 + m) * WPAD + ks * 32 + q * 8];
    int jm[4];
    #pragma unroll
    for (int reg = 0; reg < 4; reg++)
        jm[reg] = mask[n * Ln + jt * 64 + w * 16 + 4 * q + reg];
    __syncthreads();

    floatx4 Oacc[8];
    #pragma unroll
    for (int c = 0; c < 8; c++) Oacc[c] = (floatx4){0.f, 0.f, 0.f, 0.f};
    f16* Pw = &Pb[w * 16 * PBPAD];

    for (int it2 = 0; it2 < 16; it2++) {
        const f16* qsrc = Qz + ((size_t)n * Ln + it2 * 64) * Dn;
        const f16* vsrc = Vt + hoff * Dn * Ln + it2 * 64;
        for (int ii = 0; ii < 4; ii++) {
            int idx = t + 256 * ii; int r = idx >> 4, c = idx & 15;
            *(float4*)&Qb[r * WPAD + c * 8] = *(const float4*)(qsrc + (size_t)r * Dn + c * 8);
        }
        for (int ii = 0; ii < 4; ii++) {
            int idx = t + 256 * ii; int r = idx >> 3, c = idx & 7;
            *(float4*)&Vb[r * UBPAD + c * 8] = *(const float4*)(vsrc + (size_t)r * Ln + c * 8);
        }
        if (t < 64) {
            size_t rb2 = hoff * Ln + it2 * 64 + t;
            mIs[t] = rowM[rb2];
            lIs[t] = 1.0f / rowL[rb2];
            ims[t] = mask[n * Ln + it2 * 64 + t];
        }
        __syncthreads();

        // S^T tile: rows j = 4q+reg (wave strip), cols i = 16ct+m
        #pragma unroll
        for (int ct = 0; ct < 4; ct++) {
            floatx4 acc = {0.f, 0.f, 0.f, 0.f};
            #pragma unroll
            for (int ks = 0; ks < 4; ks++) {
                half8 b = *(const half8*)&Qb[(ct * 16 + m) * WPAD + ks * 32 + q * 8];
                acc = MFMA(au[ks], b, acc);
            }
            float mi = mIs[ct * 16 + m];
            float li = lIs[ct * 16 + m];
            int iv = ims[ct * 16 + m];
            #pragma unroll
            for (int reg = 0; reg < 4; reg++) {
                float p = (iv && jm[reg]) ? __expf(acc[reg] - mi) * li : 0.f;
                Pw[(4 * q + reg) * PBPAD + ct * 16 + m] = (f16)p;
            }
        }
        // O += P^T * V
        #pragma unroll
        for (int ks2 = 0; ks2 < 2; ks2++) {
            half8 ap = *(const half8*)&Pw[m * PBPAD + ks2 * 32 + q * 8];
            #pragma unroll
            for (int c = 0; c < 8; c++) {
                half8 bv = *(const half8*)&Vb[(c * 16 + m) * UBPAD + ks2 * 32 + q * 8];
                Oacc[c] = MFMA(ap, bv, Oacc[c]);
            }
        }
        __syncthreads();
    }

    f16* Mo = Macc + (hoff * Ln + jt * 64 + w * 16 + 4 * q) * Dn;
    #pragma unroll
    for (int reg = 0; reg < 4; reg++)
        #pragma unroll
        for (int c = 0; c < 8; c++) {
            f16* p = &Mo[(size_t)reg * Dn + c * 16 + m];
            *p = (f16)((float)*p + Oacc[c][reg]);
        }
}

// ---------------- combine: F_Z = x + sum_h Macc ----------------------------
__global__ void combine_kernel(const float* __restrict__ x, const f16* __restrict__ Macc,
                               float* __restrict__ out) {
    int idx = blockIdx.x * 256 + threadIdx.x;
    if (idx >= Bn * Ln * Dn) return;
    int n = idx >> 17;               // / (L*D)
    int rem = idx & (Ln * Dn - 1);
    float acc = x[idx];
    #pragma unroll
    for (int h = 0; h < Hn; h++)
        acc += (float)Macc[((size_t)(n * Hn + h)) * Ln * Dn + rem];
    out[idx] = acc;
}

__global__ void mask_out_kernel(float* __restrict__ Fz, const int* __restrict__ mask) {
    int idx = blockIdx.x * 256 + threadIdx.x;
    if (idx < Bn * Ln * Dn) {
        int row = idx / Dn;
        if (mask[row] == 0) Fz[idx] = 0.f;
    }
}

extern "C" void kernel_launch(void* const* d_in, const int* in_sizes, int n_in,
                              void* d_out, int out_size, void* d_ws, size_t ws_size,
                              hipStream_t stream) {
    const float* x       = (const float*)d_in[0];
    const int*   mask    = (const int*)d_in[1];
    const float* ternary = (const float*)d_in[2];
    const float* global_ = (const float*)d_in[3];
    float* out = (float*)d_out;
    (void)ws_size; (void)n_in; (void)in_sizes; (void)out_size;

    char* ws = (char*)d_ws;
    size_t o = 0;
    f16* Qzh = (f16*)(ws + o); o += (size_t)Bn * Ln * Dn * 2;           // 1 MB
    f16* U   = (f16*)(ws + o); o += (size_t)Bn * Hn * Ln * Dn * 2;      // 8.4 MB
    f16* Ut  = (f16*)(ws + o); o += (size_t)Bn * Hn * Ln * Dn * 2;      // 8.4 MB
    f16* Vt  = (f16*)(ws + o); o += (size_t)Bn * Hn * Ln * Dn * 2;      // 8.4 MB
    f16* TpA = (f16*)(ws + o); o += (size_t)Hn * Dn * Dn * 2;
    f16* TpB = (f16*)(ws + o); o += (size_t)Hn * Dn * Dn * 2;
    f16* GpA = (f16*)(ws + o); o += (size_t)Hn * Gn * Dn * 2;
    f16* Gpt = (f16*)(ws + o); o += (size_t)Hn * Dn * Gn * 2;
    float* rowM = (float*)(ws + o); o += (size_t)Bn * Hn * Ln * 4;
    float* rowL = (float*)(ws + o); o += (size_t)Bn * Hn * Ln * 4;
    f16* Macc = (f16*)(ws + o); o += (size_t)Bn * Hn * Ln * Dn * 2;     // 8.4 MB

    repack_kernel<<<(Dn * Dn * Hn + 255) / 256, 256, 0, stream>>>(ternary, global_, TpA, TpB, GpA, Gpt);
    softmax_rows_kernel<<<Bn * Ln, 128, 0, stream>>>(x, Qzh);

    for (int it = 0; it < NITERS; it++) {
        uv_kernel<<<dim3(Ln / 64, Hn, Bn), 256, 0, stream>>>(Qzh, TpA, TpB, U, Ut, Vt);
        msgi_kernel<<<dim3(Ln / 64, Hn, Bn), 256, 0, stream>>>(Qzh, U, Ut, GpA, Gpt, mask, Macc, rowM, rowL);
        msgj_kernel<<<dim3(Ln / 64, Hn, Bn), 256, 0, stream>>>(Qzh, U, Vt, mask, rowM, rowL, Macc);
        combine_kernel<<<(Bn * Ln * Dn + 255) / 256, 256, 0, stream>>>(x, Macc, out);
        if (it < NITERS - 1)
            softmax_rows_kernel<<<Bn * Ln, 128, 0, stream>>>(out, Qzh);
    }
    mask_out_kernel<<<(Bn * Ln * Dn + 255) / 256, 256, 0, stream>>>(out, mask);
}